// Round 17
// baseline (1147.877 us; speedup 1.0000x reference)
//
#include <hip/hip_runtime.h>

// SP_DNN: two fused 1->256->256->256->256 MLPs (sin activations) + strided rowwise dot.
// fp16 MFMA (16x16x32), fp32 accumulate.
//
// R17: clean retest of R14's A-traffic halving. Evidence: per t-iter per CU,
// MFMA demand ~620 cyc + A-delivery ~585 cyc == measured 1250 (SUM, also at
// R13's different shape) -> delivery and MFMA additive. R14 (128-row tile,
// delivery/2) nulled, but was confounded: spills (14.7MB), conflict spike,
// B-depth 0. R17 = R14 geometry with confounds fixed:
//  - block 512 thr / 8 waves / 128 rows; wave owns 32ch x 128 rows
//    (channel-split, no A duplication). A-delivery/t/CU: 585 -> 292 cyc.
//  - B depth-1 at HALF-CLUSTER granularity: bfr[2][4]; issue next half's 4
//    ds_reads before current half's 8 MFMAs (~310+cyc cover, 32 VGPR only).
//  - register diet: ~128 AGPR + ~90 VGPR ~ 220 <= 256 -> no spills.
//  - g0 = wave: free 8-way K-stagger (R16-proven clean, static t-keyed
//    slices per rule #20; runtime gs in ADDRESSES only).
// Kept: 6 alternating x/t phases, wb+layer0_t sliced into MFMA shadow,
// depth-2 A reg pipeline chaining across phases, lgkm-only barriers,
// params in LDS. LDS 138 KB -> 1 blk/CU (2 waves/SIMD).
// N=1e6: 7813 blocks, last block guards x-load/out-store.

typedef _Float16 f16x8 __attribute__((ext_vector_type(8)));
typedef _Float16 f16x4 __attribute__((ext_vector_type(4)));
typedef float f32x4 __attribute__((ext_vector_type(4)));

// Swizzled act-buffer byte offset: row m (0..127, 512 B stride), kbyte in
// [0,512). 16B unit index XORed with (m&7).
__device__ __forceinline__ int hswz(int m, int kbyte) {
    return m * 512 + ((((kbyte >> 4) ^ (m & 7)) & 31) << 4) + (kbyte & 15);
}

// Raw workgroup barrier draining LDS ops only; global loads stay in flight.
__device__ __forceinline__ void barrier_lds() {
    asm volatile("s_waitcnt lgkmcnt(0)" ::: "memory");
    __builtin_amdgcn_s_barrier();
}

// ---------------------------------------------------------------------------
// Prepack (R14-verified): W[k][n] (256x256 f32, k-major) -> fp16 fragments:
//   idx = g*8192 + w*1024 + ci*512 + l*8 + j
//   n = w*32 + ci*16 + (l&15),  k = g*32 + (l>>4)*8 + j
// ---------------------------------------------------------------------------
__global__ void prepack(const float* __restrict__ xW1, const float* __restrict__ xW2,
                        const float* __restrict__ xW3, const float* __restrict__ tW1,
                        const float* __restrict__ tW2, const float* __restrict__ tW3,
                        _Float16* __restrict__ dst)
{
    int g = blockIdx.x * 256 + threadIdx.x;   // 6*65536 threads exactly
    int L = g >> 16;
    int r = g & 65535;
    int j  = r & 7;            // bits 0-2
    int l  = (r >> 3) & 63;    // bits 3-8
    int ci = (r >> 9) & 1;     // bit 9
    int w  = (r >> 10) & 7;    // bits 10-12
    int gg = (r >> 13) & 7;    // bits 13-15
    const float* W;
    switch (L) {
        case 0: W = xW1; break;
        case 1: W = xW2; break;
        case 2: W = xW3; break;
        case 3: W = tW1; break;
        case 4: W = tW2; break;
        default: W = tW3; break;
    }
    int n = w * 32 + ci * 16 + (l & 15);
    int k = gg * 32 + ((l >> 4) & 3) * 8 + j;
    dst[g] = (_Float16)W[k * 256 + n];
}

// ---------------------------------------------------------------------------
// Main fused kernel. Block = 512 threads (8 waves), tile = 128 rows.
// Wave w owns out-channels [w*32, w*32+32) for all 128 rows.
// acc[ci][ri]: ci = ch frag (2 x 16ch), ri = row frag (8 x 16 rows).
// ---------------------------------------------------------------------------

__device__ __forceinline__ void layer0_scalar(
    float xv, const float* __restrict__ W0, const float* __restrict__ b0,
    _Float16* __restrict__ hb, int tid)
{
    int m = tid >> 2;        // 128 rows, 4 threads per row
    int q = tid & 3;
#pragma unroll
    for (int g = 0; g < 8; ++g) {
        int n0 = g * 32 + q * 8;        // 4 q-addresses -> 4 distinct banks
        f16x8 hv;
#pragma unroll
        for (int e = 0; e < 8; ++e) {
            float z = fmaf(xv, W0[n0 + e], b0[n0 + e]);
            hv[e] = (_Float16)__sinf(z);
        }
        *(f16x8*)((char*)hb + hswz(m, n0 * 2)) = hv;
    }
}

// One GEMM phase: acc = Wl x rb, iterating gs = (g0+t)&7, t = 0..7.
// Per t: two half-clusters of 8 MFMAs (ri 0-3, then 4-7).
//   [issue half1(gs) B reads] [MFMA half0] [wb slice s=2t]
//   [issue half0(gs+1) B reads] [MFMA half1] [A refill t+2] [wb slice s=2t+1]
// A: afr[2][2] depth-2 register pipeline; t=6/7 chain to Wnext (g0, g0+1).
// B: bfr[2][4] half-cluster depth-1 (load precedes use by >=1 half-cluster).
// MODE 1: wb slice s=2t+half: frag (cw=s>>3, rw=s&7) -- static after unroll.
// MODE 2: layer0_t, one 8-ch group per t (n0 = t*32+q*8, static).
template<int MODE>   // 0 plain, 1 writeback, 2 layer0-slice
__device__ __forceinline__ void gemm_phase(
    const _Float16* __restrict__ Wl,
    const _Float16* __restrict__ Wnext,    // nullptr at the end
    const _Float16* __restrict__ rb,       // LDS read buffer (activations)
    f32x4 acc[2][8], f16x8 afr[2][2],
    f32x4 wacc[2][8],                      // MODE 1: prev phase's acc
    const float* __restrict__ wbias,       // MODE 1: LDS bias for wacc
    _Float16* __restrict__ wb_lds,         // MODE 1/2: LDS write target
    float xv,                              // MODE 2: scalar input
    const float* __restrict__ W0,          // MODE 2: LDS 1->256 weights
    const float* __restrict__ b0,          // MODE 2: LDS bias
    int tid, int lane, int ln, int quad, int wave, int g0)
{
    f32x4 zero = {0.f, 0.f, 0.f, 0.f};
#pragma unroll
    for (int ci = 0; ci < 2; ++ci)
#pragma unroll
        for (int ri = 0; ri < 8; ++ri)
            acc[ci][ri] = zero;

    const _Float16* abase = Wl + wave * 1024 + lane * 8;

    f16x8 bfr[2][4];
#pragma unroll
    for (int r = 0; r < 4; ++r)          // prologue: half0 (ri 0-3) of gs(0)
        bfr[0][r] = *(const f16x8*)((const char*)rb +
                                    hswz(16 * r + ln, g0 * 64 + quad * 16));

#pragma unroll
    for (int t = 0; t < 8; ++t) {
        const int gs  = (g0 + t) & 7;        // runtime ADDRESS only
        const int gs1 = (g0 + t + 1) & 7;

        // issue half1 (ri 4-7) of gs into buf1
#pragma unroll
        for (int r = 0; r < 4; ++r)
            bfr[1][r] = *(const f16x8*)((const char*)rb +
                            hswz(16 * (r + 4) + ln, gs * 64 + quad * 16));

        __builtin_amdgcn_s_setprio(1);       // MFMA half0: ri 0-3
#pragma unroll
        for (int ci = 0; ci < 2; ++ci)
#pragma unroll
            for (int r = 0; r < 4; ++r)
                acc[ci][r] = __builtin_amdgcn_mfma_f32_16x16x32_f16(
                    afr[t & 1][ci], bfr[0][r], acc[ci][r], 0, 0, 0);
        __builtin_amdgcn_s_setprio(0);

        if (MODE == 1) {                     // wb slice s = 2t (static)
            const int s = 2 * t, cw = s >> 3, rw = s & 7;
            const int nb = wave * 32 + cw * 16 + quad * 4;
            f32x4 bv = *(const f32x4*)&wbias[nb];
            f16x4 hv;
            hv[0] = (_Float16)__sinf(wacc[cw][rw][0] + bv[0]);
            hv[1] = (_Float16)__sinf(wacc[cw][rw][1] + bv[1]);
            hv[2] = (_Float16)__sinf(wacc[cw][rw][2] + bv[2]);
            hv[3] = (_Float16)__sinf(wacc[cw][rw][3] + bv[3]);
            *(f16x4*)((char*)wb_lds + hswz(16 * rw + ln, nb * 2)) = hv;
        }

        // issue half0 (ri 0-3) of gs+1 into buf0 (for next t)
        if (t < 7) {
#pragma unroll
            for (int r = 0; r < 4; ++r)
                bfr[0][r] = *(const f16x8*)((const char*)rb +
                                hswz(16 * r + ln, gs1 * 64 + quad * 16));
        }

        __builtin_amdgcn_s_setprio(1);       // MFMA half1: ri 4-7
#pragma unroll
        for (int ci = 0; ci < 2; ++ci)
#pragma unroll
            for (int r = 0; r < 4; ++r)
                acc[ci][r + 4] = __builtin_amdgcn_mfma_f32_16x16x32_f16(
                    afr[t & 1][ci], bfr[1][r], acc[ci][r + 4], 0, 0, 0);
        __builtin_amdgcn_s_setprio(0);

        // A refill buf[t&1] for t+2; t=6/7 chain to Wnext's (g0, g0+1).
        if (t < 6) {
            const int gs2 = (g0 + t + 2) & 7;
#pragma unroll
            for (int ci = 0; ci < 2; ++ci)
                afr[t & 1][ci] = *(const f16x8*)(abase + gs2 * 8192 + ci * 512);
        } else if (Wnext) {
            const int gs2 = (g0 + t + 2) & 7;   // t=6 -> g0, t=7 -> g0+1
#pragma unroll
            for (int ci = 0; ci < 2; ++ci)
                afr[t & 1][ci] = *(const f16x8*)(Wnext + gs2 * 8192 +
                                                 wave * 1024 + lane * 8 + ci * 512);
        }

        if (MODE == 1) {                     // wb slice s = 2t+1 (static)
            const int s = 2 * t + 1, cw = s >> 3, rw = s & 7;
            const int nb = wave * 32 + cw * 16 + quad * 4;
            f32x4 bv = *(const f32x4*)&wbias[nb];
            f16x4 hv;
            hv[0] = (_Float16)__sinf(wacc[cw][rw][0] + bv[0]);
            hv[1] = (_Float16)__sinf(wacc[cw][rw][1] + bv[1]);
            hv[2] = (_Float16)__sinf(wacc[cw][rw][2] + bv[2]);
            hv[3] = (_Float16)__sinf(wacc[cw][rw][3] + bv[3]);
            *(f16x4*)((char*)wb_lds + hswz(16 * rw + ln, nb * 2)) = hv;
        } else if (MODE == 2) {              // layer0 slice keyed by t (static)
            const int m = tid >> 2, q = tid & 3;
            const int n0 = t * 32 + q * 8;
            f16x8 hv;
#pragma unroll
            for (int e = 0; e < 8; ++e) {
                float z = fmaf(xv, W0[n0 + e], b0[n0 + e]);
                hv[e] = (_Float16)__sinf(z);
            }
            *(f16x8*)((char*)wb_lds + hswz(m, n0 * 2)) = hv;
        }
    }
}

__global__ __launch_bounds__(512, 2)
void mlp_fused(const float* __restrict__ x,
               const float* __restrict__ xW0, const float* __restrict__ xb0,
               const float* __restrict__ xb1, const float* __restrict__ xb2,
               const float* __restrict__ xb3,
               const float* __restrict__ tW0, const float* __restrict__ tb0,
               const float* __restrict__ tb1, const float* __restrict__ tb2,
               const float* __restrict__ tb3,
               const _Float16* __restrict__ Wp,
               float* __restrict__ out, int N)
{
    __shared__ __align__(16) _Float16 hbuf[2][128 * 256];  // 2 x 64 KB acts
    __shared__ __align__(16) float    params[10 * 256];    // 10 KB small params

    const int tid = threadIdx.x;
    const int lane = tid & 63;
    const int wave = tid >> 6;       // 0..7
    const int ln = lane & 15;
    const int quad = lane >> 4;
    const int row0 = blockIdx.x * 128;
    const int g0 = wave;             // 8 waves = perfect 8-way K-stagger

    // Preload all small params to LDS (R14-verified 5+5 split).
    // segs: 0 xW0, 1 xb0, 2 tW0, 3 tb0, 4 xb1, 5 xb2, 6 xb3, 7 tb1, 8 tb2, 9 tb3
    {
        const float* psrc[10] = {xW0, xb0, tW0, tb0, xb1, xb2, xb3, tb1, tb2, tb3};
        int half = tid >> 8, e = tid & 255;      // half 0: segs 0-4, half 1: 5-9
#pragma unroll
        for (int s = 0; s < 5; ++s)
            params[(half * 5 + s) * 256 + e] = psrc[half * 5 + s][e];
    }
    const int myrow = row0 + (tid >> 2);
    const float2 xv2 = (myrow < N) ? ((const float2*)x)[myrow]
                                   : make_float2(0.f, 0.f);

    f32x4 xacc[2][8], tacc[2][8];    // 128 AGPR
    f16x8 afr[2][2];                 // A-fragment register double-buffer (16 VGPR)

    // Prologue: xW1 (g0) -> buf0, (g0+1) -> buf1; land during layer0_x.
#pragma unroll
    for (int s = 0; s < 2; ++s) {
        const int gs = (g0 + s) & 7;
#pragma unroll
        for (int ci = 0; ci < 2; ++ci)
            afr[s][ci] = *(const f16x8*)(Wp + gs * 8192 + wave * 1024 +
                                         lane * 8 + ci * 512);
    }
    barrier_lds();                    // params visible to all waves

    // ----- layer0_x -----
    layer0_scalar(xv2.x, &params[0], &params[256], hbuf[0], tid);
    barrier_lds();                    // x acts visible

    // ----- 6 alternating GEMM phases -----
    // P1: x1; layer0_t sliced in -> hbuf[1]
    gemm_phase<2>(Wp + 0 * 65536, Wp + 3 * 65536, hbuf[0], xacc, afr,
                  nullptr, nullptr, hbuf[1],
                  xv2.y, &params[2 * 256], &params[3 * 256],
                  tid, lane, ln, quad, wave, g0);
    barrier_lds();
    // P2: t1 || wb_x1 -> hbuf[0]
    gemm_phase<1>(Wp + 3 * 65536, Wp + 1 * 65536, hbuf[1], tacc, afr,
                  xacc, &params[4 * 256], hbuf[0],
                  0.f, nullptr, nullptr, tid, lane, ln, quad, wave, g0);
    barrier_lds();
    // P3: x2 || wb_t1 -> hbuf[1]
    gemm_phase<1>(Wp + 1 * 65536, Wp + 4 * 65536, hbuf[0], xacc, afr,
                  tacc, &params[7 * 256], hbuf[1],
                  0.f, nullptr, nullptr, tid, lane, ln, quad, wave, g0);
    barrier_lds();
    // P4: t2 || wb_x2 -> hbuf[0]
    gemm_phase<1>(Wp + 4 * 65536, Wp + 2 * 65536, hbuf[1], tacc, afr,
                  xacc, &params[5 * 256], hbuf[0],
                  0.f, nullptr, nullptr, tid, lane, ln, quad, wave, g0);
    barrier_lds();
    // P5: x3 || wb_t2 -> hbuf[1]
    gemm_phase<1>(Wp + 2 * 65536, Wp + 5 * 65536, hbuf[0], xacc, afr,
                  tacc, &params[8 * 256], hbuf[1],
                  0.f, nullptr, nullptr, tid, lane, ln, quad, wave, g0);
    barrier_lds();
    // P6: t3
    gemm_phase<0>(Wp + 5 * 65536, nullptr, hbuf[1], tacc, afr,
                  nullptr, nullptr, nullptr,
                  0.f, nullptr, nullptr, tid, lane, ln, quad, wave, g0);

    // ----- combine: even/odd strided dot, fp32 (R14-verified) -----
    // channel = wave*32 + ci*16 + quad*4 + r (parity = r&1); row = 16*ri+ln.
    const float* xb3l = &params[6 * 256];
    const float* tb3l = &params[9 * 256];
    float ev[8], od[8];
#pragma unroll
    for (int ri = 0; ri < 8; ++ri) { ev[ri] = 0.f; od[ri] = 0.f; }
#pragma unroll
    for (int ci = 0; ci < 2; ++ci) {
        int nb = wave * 32 + ci * 16 + quad * 4;
        f32x4 xb = *(const f32x4*)&xb3l[nb];
        f32x4 tb = *(const f32x4*)&tb3l[nb];
#pragma unroll
        for (int ri = 0; ri < 8; ++ri) {
            float a0 = xacc[ci][ri][0] + xb[0], c0 = tacc[ci][ri][0] + tb[0];
            float a1 = xacc[ci][ri][1] + xb[1], c1 = tacc[ci][ri][1] + tb[1];
            float a2 = xacc[ci][ri][2] + xb[2], c2 = tacc[ci][ri][2] + tb[2];
            float a3 = xacc[ci][ri][3] + xb[3], c3 = tacc[ci][ri][3] + tb[3];
            ev[ri] += a0 * c0 + a2 * c2;     // channel parity = reg index parity
            od[ri] += a1 * c1 + a3 * c3;
        }
    }
#pragma unroll
    for (int ri = 0; ri < 8; ++ri) {         // reduce over the 4 quads
        ev[ri] += __shfl_xor(ev[ri], 16, 64);
        ev[ri] += __shfl_xor(ev[ri], 32, 64);
        od[ri] += __shfl_xor(od[ri], 16, 64);
        od[ri] += __shfl_xor(od[ri], 32, 64);
    }

    // hbuf[0] dead: its last readers (P5) all passed the P5->P6 barrier.
    float* red = (float*)hbuf[0];
    if (lane < 16) {
#pragma unroll
        for (int ri = 0; ri < 8; ++ri) {
            red[wave * 256 + ri * 32 + ln * 2 + 0] = ev[ri];
            red[wave * 256 + ri * 32 + ln * 2 + 1] = od[ri];
        }
    }
    __syncthreads();
    if (tid < 256) {                         // 1 thread per (row, parity)
        int p = tid & 1, row = tid >> 1;     // row 0..127
        int base = (row >> 4) * 32 + (row & 15) * 2 + p;
        float s = 0.f;
#pragma unroll
        for (int w = 0; w < 8; ++w)          // sum the 8 wave partials
            s += red[w * 256 + base];
        if (row0 + row < N)
            out[(row0 + row) * 2 + p] = s;
    }
}

// ---------------------------------------------------------------------------
extern "C" void kernel_launch(void* const* d_in, const int* in_sizes, int n_in,
                              void* d_out, int out_size, void* d_ws, size_t ws_size,
                              hipStream_t stream)
{
    const float* x   = (const float*)d_in[0];
    const float* xW0 = (const float*)d_in[1];
    const float* xb0 = (const float*)d_in[2];
    const float* xW1 = (const float*)d_in[3];
    const float* xb1 = (const float*)d_in[4];
    const float* xW2 = (const float*)d_in[5];
    const float* xb2 = (const float*)d_in[6];
    const float* xW3 = (const float*)d_in[7];
    const float* xb3 = (const float*)d_in[8];
    const float* tW0 = (const float*)d_in[9];
    const float* tb0 = (const float*)d_in[10];
    const float* tW1 = (const float*)d_in[11];
    const float* tb1 = (const float*)d_in[12];
    const float* tW2 = (const float*)d_in[13];
    const float* tb2 = (const float*)d_in[14];
    const float* tW3 = (const float*)d_in[15];
    const float* tb3 = (const float*)d_in[16];

    _Float16* Wp = (_Float16*)d_ws;          // 6*65536 fp16 = 768 KB
    const int N = in_sizes[0] / 2;           // 1,000,000
    const int nblk = (N + 127) / 128;        // 7813 (last block: 64 valid rows)

    prepack<<<1536, 256, 0, stream>>>(xW1, xW2, xW3, tW1, tW2, tW3, Wp);
    mlp_fused<<<nblk, 512, 0, stream>>>(x, xW0, xb0, xb1, xb2, xb3,
                                        tW0, tb0, tb1, tb2, tb3,
                                        Wp, (float*)d_out, N);
}

// Round 19
// 851.552 us; speedup vs baseline: 1.3480x; 1.3480x over previous
//
#include <hip/hip_runtime.h>

// SP_DNN: two fused 1->256->256->256->256 MLPs (sin activations) + strided rowwise dot.
// fp16 MFMA (16x16x32), fp32 accumulate.
//
// R19 = R18 resubmitted verbatim (R18's bench died to a transient container
// failure, not a kernel verdict; kernel audit found no fault candidates:
// LDS 138<=160 KB, legal launch_bounds, guarded tail block).
//
// R18 rationale: third attempt at the 128-row tile (A-L2-traffic halving:
// 12 -> 6 GB). R14/R17 both spilled because __launch_bounds__(512,2)'s
// second arg is min WAVES PER EU (not blocks/CU): it capped the unified file
// at 128 arch VGPRs while demand is ~100 arch + 128 AGPR. Fix:
// __launch_bounds__(512,1) -- the 138 KB LDS already limits to 1 block/CU
// (8 waves, 2/SIMD), so the cap was pure downside.
// K-stagger dropped (R16 clean null) -> all-static g indices; param preload
// with static seg index (rule #20).
// Geometry: 512 thr / 8 waves / 128 rows; wave owns 32ch x 128 rows
// (channel-split, no A duplication). Kept: 6 alternating x/t phases,
// wb+layer0_t sliced into MFMA shadow (static keys), depth-2 A register
// pipeline chaining across phases, half-cluster depth-1 B (32 VGPR),
// lgkm-only barriers, params in LDS.
// N=1e6: 7813 blocks, last block guards x-load/out-store.

typedef _Float16 f16x8 __attribute__((ext_vector_type(8)));
typedef _Float16 f16x4 __attribute__((ext_vector_type(4)));
typedef float f32x4 __attribute__((ext_vector_type(4)));

// Swizzled act-buffer byte offset: row m (0..127, 512 B stride), kbyte in
// [0,512). 16B unit index XORed with (m&7).
__device__ __forceinline__ int hswz(int m, int kbyte) {
    return m * 512 + ((((kbyte >> 4) ^ (m & 7)) & 31) << 4) + (kbyte & 15);
}

// Raw workgroup barrier draining LDS ops only; global loads stay in flight.
__device__ __forceinline__ void barrier_lds() {
    asm volatile("s_waitcnt lgkmcnt(0)" ::: "memory");
    __builtin_amdgcn_s_barrier();
}

// ---------------------------------------------------------------------------
// Prepack (R14-verified): W[k][n] (256x256 f32, k-major) -> fp16 fragments:
//   idx = g*8192 + w*1024 + ci*512 + l*8 + j
//   n = w*32 + ci*16 + (l&15),  k = g*32 + (l>>4)*8 + j
// ---------------------------------------------------------------------------
__global__ void prepack(const float* __restrict__ xW1, const float* __restrict__ xW2,
                        const float* __restrict__ xW3, const float* __restrict__ tW1,
                        const float* __restrict__ tW2, const float* __restrict__ tW3,
                        _Float16* __restrict__ dst)
{
    int g = blockIdx.x * 256 + threadIdx.x;   // 6*65536 threads exactly
    int L = g >> 16;
    int r = g & 65535;
    int j  = r & 7;            // bits 0-2
    int l  = (r >> 3) & 63;    // bits 3-8
    int ci = (r >> 9) & 1;     // bit 9
    int w  = (r >> 10) & 7;    // bits 10-12
    int gg = (r >> 13) & 7;    // bits 13-15
    const float* W;
    switch (L) {
        case 0: W = xW1; break;
        case 1: W = xW2; break;
        case 2: W = xW3; break;
        case 3: W = tW1; break;
        case 4: W = tW2; break;
        default: W = tW3; break;
    }
    int n = w * 32 + ci * 16 + (l & 15);
    int k = gg * 32 + ((l >> 4) & 3) * 8 + j;
    dst[g] = (_Float16)W[k * 256 + n];
}

// ---------------------------------------------------------------------------
// Main fused kernel. Block = 512 threads (8 waves), tile = 128 rows.
// Wave w owns out-channels [w*32, w*32+32) for all 128 rows.
// acc[ci][ri]: ci = ch frag (2 x 16ch), ri = row frag (8 x 16 rows).
// ---------------------------------------------------------------------------

__device__ __forceinline__ void layer0_scalar(
    float xv, const float* __restrict__ W0, const float* __restrict__ b0,
    _Float16* __restrict__ hb, int tid)
{
    int m = tid >> 2;        // 128 rows, 4 threads per row
    int q = tid & 3;
#pragma unroll
    for (int g = 0; g < 8; ++g) {
        int n0 = g * 32 + q * 8;        // 4 q-addresses -> 4 distinct banks
        f16x8 hv;
#pragma unroll
        for (int e = 0; e < 8; ++e) {
            float z = fmaf(xv, W0[n0 + e], b0[n0 + e]);
            hv[e] = (_Float16)__sinf(z);
        }
        *(f16x8*)((char*)hb + hswz(m, n0 * 2)) = hv;
    }
}

// One GEMM phase: acc = Wl x rb, g = 0..7 (static). Per g: two half-clusters
// of 8 MFMAs (ri 0-3, then 4-7):
//   [issue half1(g) B reads] [MFMA half0] [wb slice s=2g]
//   [issue half0(g+1) B reads] [MFMA half1] [A refill g+2] [wb slice s=2g+1]
// A: afr[2][2] depth-2 register pipeline; g=6/7 chain to Wnext's g0/g1.
// B: bfr[2][4] half-cluster depth-1 (load precedes use by 1 half-cluster).
// MODE 1: wb slice s: frag (cw=s>>3, rw=s&7) -- static after unroll.
// MODE 2: layer0_t, one 8-ch group per g (n0 = g*32+q*8, static).
template<int MODE>   // 0 plain, 1 writeback, 2 layer0-slice
__device__ __forceinline__ void gemm_phase(
    const _Float16* __restrict__ Wl,
    const _Float16* __restrict__ Wnext,    // nullptr at the end
    const _Float16* __restrict__ rb,       // LDS read buffer (activations)
    f32x4 acc[2][8], f16x8 afr[2][2],
    f32x4 wacc[2][8],                      // MODE 1: prev phase's acc
    const float* __restrict__ wbias,       // MODE 1: LDS bias for wacc
    _Float16* __restrict__ wb_lds,         // MODE 1/2: LDS write target
    float xv,                              // MODE 2: scalar input
    const float* __restrict__ W0,          // MODE 2: LDS 1->256 weights
    const float* __restrict__ b0,          // MODE 2: LDS bias
    int tid, int lane, int ln, int quad, int wave)
{
    f32x4 zero = {0.f, 0.f, 0.f, 0.f};
#pragma unroll
    for (int ci = 0; ci < 2; ++ci)
#pragma unroll
        for (int ri = 0; ri < 8; ++ri)
            acc[ci][ri] = zero;

    const _Float16* abase = Wl + wave * 1024 + lane * 8;

    f16x8 bfr[2][4];
#pragma unroll
    for (int r = 0; r < 4; ++r)          // prologue: half0 (ri 0-3) of g=0
        bfr[0][r] = *(const f16x8*)((const char*)rb +
                                    hswz(16 * r + ln, quad * 16));

#pragma unroll
    for (int g = 0; g < 8; ++g) {
        // issue half1 (ri 4-7) of g into buf1
#pragma unroll
        for (int r = 0; r < 4; ++r)
            bfr[1][r] = *(const f16x8*)((const char*)rb +
                            hswz(16 * (r + 4) + ln, g * 64 + quad * 16));

        __builtin_amdgcn_s_setprio(1);       // MFMA half0: ri 0-3
#pragma unroll
        for (int ci = 0; ci < 2; ++ci)
#pragma unroll
            for (int r = 0; r < 4; ++r)
                acc[ci][r] = __builtin_amdgcn_mfma_f32_16x16x32_f16(
                    afr[g & 1][ci], bfr[0][r], acc[ci][r], 0, 0, 0);
        __builtin_amdgcn_s_setprio(0);

        if (MODE == 1) {                     // wb slice s = 2g (static)
            const int s = 2 * g, cw = s >> 3, rw = s & 7;
            const int nb = wave * 32 + cw * 16 + quad * 4;
            f32x4 bv = *(const f32x4*)&wbias[nb];
            f16x4 hv;
            hv[0] = (_Float16)__sinf(wacc[cw][rw][0] + bv[0]);
            hv[1] = (_Float16)__sinf(wacc[cw][rw][1] + bv[1]);
            hv[2] = (_Float16)__sinf(wacc[cw][rw][2] + bv[2]);
            hv[3] = (_Float16)__sinf(wacc[cw][rw][3] + bv[3]);
            *(f16x4*)((char*)wb_lds + hswz(16 * rw + ln, nb * 2)) = hv;
        }

        // issue half0 (ri 0-3) of g+1 into buf0 (for next g)
        if (g < 7) {
#pragma unroll
            for (int r = 0; r < 4; ++r)
                bfr[0][r] = *(const f16x8*)((const char*)rb +
                                hswz(16 * r + ln, (g + 1) * 64 + quad * 16));
        }

        __builtin_amdgcn_s_setprio(1);       // MFMA half1: ri 4-7
#pragma unroll
        for (int ci = 0; ci < 2; ++ci)
#pragma unroll
            for (int r = 0; r < 4; ++r)
                acc[ci][r + 4] = __builtin_amdgcn_mfma_f32_16x16x32_f16(
                    afr[g & 1][ci], bfr[1][r], acc[ci][r + 4], 0, 0, 0);
        __builtin_amdgcn_s_setprio(0);

        // A refill buf[g&1] for g+2; g=6/7 chain to Wnext's g0/g1.
        if (g < 6) {
#pragma unroll
            for (int ci = 0; ci < 2; ++ci)
                afr[g & 1][ci] = *(const f16x8*)(abase + (g + 2) * 8192 + ci * 512);
        } else if (Wnext) {
#pragma unroll
            for (int ci = 0; ci < 2; ++ci)
                afr[g & 1][ci] = *(const f16x8*)(Wnext + (g - 6) * 8192 +
                                                 wave * 1024 + lane * 8 + ci * 512);
        }

        if (MODE == 1) {                     // wb slice s = 2g+1 (static)
            const int s = 2 * g + 1, cw = s >> 3, rw = s & 7;
            const int nb = wave * 32 + cw * 16 + quad * 4;
            f32x4 bv = *(const f32x4*)&wbias[nb];
            f16x4 hv;
            hv[0] = (_Float16)__sinf(wacc[cw][rw][0] + bv[0]);
            hv[1] = (_Float16)__sinf(wacc[cw][rw][1] + bv[1]);
            hv[2] = (_Float16)__sinf(wacc[cw][rw][2] + bv[2]);
            hv[3] = (_Float16)__sinf(wacc[cw][rw][3] + bv[3]);
            *(f16x4*)((char*)wb_lds + hswz(16 * rw + ln, nb * 2)) = hv;
        } else if (MODE == 2) {              // layer0 slice keyed by g (static)
            const int m = tid >> 2, q = tid & 3;
            const int n0 = g * 32 + q * 8;
            f16x8 hv;
#pragma unroll
            for (int e = 0; e < 8; ++e) {
                float z = fmaf(xv, W0[n0 + e], b0[n0 + e]);
                hv[e] = (_Float16)__sinf(z);
            }
            *(f16x8*)((char*)wb_lds + hswz(m, n0 * 2)) = hv;
        }
    }
}

__global__ __launch_bounds__(512, 1)
void mlp_fused(const float* __restrict__ x,
               const float* __restrict__ xW0, const float* __restrict__ xb0,
               const float* __restrict__ xb1, const float* __restrict__ xb2,
               const float* __restrict__ xb3,
               const float* __restrict__ tW0, const float* __restrict__ tb0,
               const float* __restrict__ tb1, const float* __restrict__ tb2,
               const float* __restrict__ tb3,
               const _Float16* __restrict__ Wp,
               float* __restrict__ out, int N)
{
    __shared__ __align__(16) _Float16 hbuf[2][128 * 256];  // 2 x 64 KB acts
    __shared__ __align__(16) float    params[10 * 256];    // 10 KB small params

    const int tid = threadIdx.x;
    const int lane = tid & 63;
    const int wave = tid >> 6;       // 0..7
    const int ln = lane & 15;
    const int quad = lane >> 4;
    const int row0 = blockIdx.x * 128;

    // Preload all small params to LDS -- STATIC seg index (rule #20).
    // segs: 0 xW0, 1 xb0, 2 tW0, 3 tb0, 4 xb1, 5 xb2, 6 xb3, 7 tb1, 8 tb2, 9 tb3
    if (tid < 256) {
        const float* psrc[10] = {xW0, xb0, tW0, tb0, xb1, xb2, xb3, tb1, tb2, tb3};
#pragma unroll
        for (int s = 0; s < 10; ++s)
            params[s * 256 + tid] = psrc[s][tid];
    }
    const int myrow = row0 + (tid >> 2);
    const float2 xv2 = (myrow < N) ? ((const float2*)x)[myrow]
                                   : make_float2(0.f, 0.f);

    f32x4 xacc[2][8], tacc[2][8];    // 128 AGPR
    f16x8 afr[2][2];                 // A-fragment register double-buffer (16 VGPR)

    // Prologue: xW1 g0 -> buf0, g1 -> buf1; land during layer0_x.
#pragma unroll
    for (int s = 0; s < 2; ++s)
#pragma unroll
        for (int ci = 0; ci < 2; ++ci)
            afr[s][ci] = *(const f16x8*)(Wp + s * 8192 + wave * 1024 +
                                         lane * 8 + ci * 512);
    barrier_lds();                    // params visible to all waves

    // ----- layer0_x -----
    layer0_scalar(xv2.x, &params[0], &params[256], hbuf[0], tid);
    barrier_lds();                    // x acts visible

    // ----- 6 alternating GEMM phases -----
    // P1: x1; layer0_t sliced in -> hbuf[1]
    gemm_phase<2>(Wp + 0 * 65536, Wp + 3 * 65536, hbuf[0], xacc, afr,
                  nullptr, nullptr, hbuf[1],
                  xv2.y, &params[2 * 256], &params[3 * 256],
                  tid, lane, ln, quad, wave);
    barrier_lds();
    // P2: t1 || wb_x1 -> hbuf[0]
    gemm_phase<1>(Wp + 3 * 65536, Wp + 1 * 65536, hbuf[1], tacc, afr,
                  xacc, &params[4 * 256], hbuf[0],
                  0.f, nullptr, nullptr, tid, lane, ln, quad, wave);
    barrier_lds();
    // P3: x2 || wb_t1 -> hbuf[1]
    gemm_phase<1>(Wp + 1 * 65536, Wp + 4 * 65536, hbuf[0], xacc, afr,
                  tacc, &params[7 * 256], hbuf[1],
                  0.f, nullptr, nullptr, tid, lane, ln, quad, wave);
    barrier_lds();
    // P4: t2 || wb_x2 -> hbuf[0]
    gemm_phase<1>(Wp + 4 * 65536, Wp + 2 * 65536, hbuf[1], tacc, afr,
                  xacc, &params[5 * 256], hbuf[0],
                  0.f, nullptr, nullptr, tid, lane, ln, quad, wave);
    barrier_lds();
    // P5: x3 || wb_t2 -> hbuf[1]
    gemm_phase<1>(Wp + 2 * 65536, Wp + 5 * 65536, hbuf[0], xacc, afr,
                  tacc, &params[8 * 256], hbuf[1],
                  0.f, nullptr, nullptr, tid, lane, ln, quad, wave);
    barrier_lds();
    // P6: t3
    gemm_phase<0>(Wp + 5 * 65536, nullptr, hbuf[1], tacc, afr,
                  nullptr, nullptr, nullptr,
                  0.f, nullptr, nullptr, tid, lane, ln, quad, wave);

    // ----- combine: even/odd strided dot, fp32 (R14-verified) -----
    // channel = wave*32 + ci*16 + quad*4 + r (parity = r&1); row = 16*ri+ln.
    const float* xb3l = &params[6 * 256];
    const float* tb3l = &params[9 * 256];
    float ev[8], od[8];
#pragma unroll
    for (int ri = 0; ri < 8; ++ri) { ev[ri] = 0.f; od[ri] = 0.f; }
#pragma unroll
    for (int ci = 0; ci < 2; ++ci) {
        int nb = wave * 32 + ci * 16 + quad * 4;
        f32x4 xb = *(const f32x4*)&xb3l[nb];
        f32x4 tb = *(const f32x4*)&tb3l[nb];
#pragma unroll
        for (int ri = 0; ri < 8; ++ri) {
            float a0 = xacc[ci][ri][0] + xb[0], c0 = tacc[ci][ri][0] + tb[0];
            float a1 = xacc[ci][ri][1] + xb[1], c1 = tacc[ci][ri][1] + tb[1];
            float a2 = xacc[ci][ri][2] + xb[2], c2 = tacc[ci][ri][2] + tb[2];
            float a3 = xacc[ci][ri][3] + xb[3], c3 = tacc[ci][ri][3] + tb[3];
            ev[ri] += a0 * c0 + a2 * c2;     // channel parity = reg index parity
            od[ri] += a1 * c1 + a3 * c3;
        }
    }
#pragma unroll
    for (int ri = 0; ri < 8; ++ri) {         // reduce over the 4 quads
        ev[ri] += __shfl_xor(ev[ri], 16, 64);
        ev[ri] += __shfl_xor(ev[ri], 32, 64);
        od[ri] += __shfl_xor(od[ri], 16, 64);
        od[ri] += __shfl_xor(od[ri], 32, 64);
    }

    // hbuf[0] dead: its last readers (P5) all passed the P5->P6 barrier.
    float* red = (float*)hbuf[0];
    if (lane < 16) {
#pragma unroll
        for (int ri = 0; ri < 8; ++ri) {
            red[wave * 256 + ri * 32 + ln * 2 + 0] = ev[ri];
            red[wave * 256 + ri * 32 + ln * 2 + 1] = od[ri];
        }
    }
    __syncthreads();
    if (tid < 256) {                         // 1 thread per (row, parity)
        int p = tid & 1, row = tid >> 1;     // row 0..127
        int base = (row >> 4) * 32 + (row & 15) * 2 + p;
        float s = 0.f;
#pragma unroll
        for (int w = 0; w < 8; ++w)          // sum the 8 wave partials
            s += red[w * 256 + base];
        if (row0 + row < N)
            out[(row0 + row) * 2 + p] = s;
    }
}

// ---------------------------------------------------------------------------
extern "C" void kernel_launch(void* const* d_in, const int* in_sizes, int n_in,
                              void* d_out, int out_size, void* d_ws, size_t ws_size,
                              hipStream_t stream)
{
    const float* x   = (const float*)d_in[0];
    const float* xW0 = (const float*)d_in[1];
    const float* xb0 = (const float*)d_in[2];
    const float* xW1 = (const float*)d_in[3];
    const float* xb1 = (const float*)d_in[4];
    const float* xW2 = (const float*)d_in[5];
    const float* xb2 = (const float*)d_in[6];
    const float* xW3 = (const float*)d_in[7];
    const float* xb3 = (const float*)d_in[8];
    const float* tW0 = (const float*)d_in[9];
    const float* tb0 = (const float*)d_in[10];
    const float* tW1 = (const float*)d_in[11];
    const float* tb1 = (const float*)d_in[12];
    const float* tW2 = (const float*)d_in[13];
    const float* tb2 = (const float*)d_in[14];
    const float* tW3 = (const float*)d_in[15];
    const float* tb3 = (const float*)d_in[16];

    _Float16* Wp = (_Float16*)d_ws;          // 6*65536 fp16 = 768 KB
    const int N = in_sizes[0] / 2;           // 1,000,000
    const int nblk = (N + 127) / 128;        // 7813 (last block: 64 valid rows)

    prepack<<<1536, 256, 0, stream>>>(xW1, xW2, xW3, tW1, tW2, tW3, Wp);
    mlp_fused<<<nblk, 512, 0, stream>>>(x, xW0, xb0, xb1, xb2, xb3,
                                        tW0, tb0, tb1, tb2, tb3,
                                        Wp, (float*)d_out, N);
}

// Round 20
// 843.628 us; speedup vs baseline: 1.3606x; 1.0094x over previous
//
#include <hip/hip_runtime.h>

// SP_DNN: two fused 1->256->256->256->256 MLPs (sin activations) + strided rowwise dot.
// fp16 MFMA (16x16x32), fp32 accumulate.
//
// R20 = R11 reverted verbatim -- the session-best verified kernel (808 us,
// prof 768, MfmaUtil 50.6%). Subsequent experiments all failed to beat it:
//   R12/R13 (32x32x16 + conflict-free swizzle): regs at cap, spill, 955us;
//     conflicts 7.2e7->2.4e7 bought nothing (they were free 2-way aliases).
//   R15/R16 (K-stagger): R15 spilled via rule-#20; R16 clean -> NULL (814).
//   R14/R17/R19 (128-row tile, A-L2-traffic halved 12->6 GB): three tries,
//     cleanest (R19) still 843 prof -- delivery BW was not the limiter.
// Ceiling model: at 2 waves/SIMD each wave alternates ~78cyc MFMA cluster
// with ~78cyc of non-MFMA issue (B ds_reads, A refills, wb slices, addr
// VALU); two waves interleave to a ~50% MfmaUtil fixed point (R10/R11/R16/
// R19 all land 50.6-51.5%). Breaking it needs 4 waves/SIMD = <=128 regs/wave
// -- unreachable with 128 AGPR of dual-MLP accumulator state (every coercion
// attempt spilled: R1/R4/R5/R14/R17/R19).
//
// Structure: depth-2 A register prefetch chaining across phases (R9),
// 6 alternating x/t GEMM phases with the other MLP's sin+writeback and
// layer0_t sliced into the MFMA issue shadow (R10), depth-1 B double-buffer
// (R11), lgkm-only raw barriers (A loads stay in flight), params in LDS,
// layer0 bank-fix split, hswz XOR swizzle, 2 blocks/CU.

typedef _Float16 f16x8 __attribute__((ext_vector_type(8)));
typedef _Float16 f16x4 __attribute__((ext_vector_type(4)));
typedef float f32x4 __attribute__((ext_vector_type(4)));

// Swizzled act-buffer byte offset: row m (0..63, 512 B stride), kbyte in
// [0,512). 16B unit index XORed with (m&7): any 8-lane chunk of a B-read
// covers all 32 banks exactly once; writeback/layer0 <=2-way (free).
__device__ __forceinline__ int hswz(int m, int kbyte) {
    return m * 512 + ((((kbyte >> 4) ^ (m & 7)) & 31) << 4) + (kbyte & 15);
}

// Raw workgroup barrier draining LDS ops only; global loads stay in flight.
__device__ __forceinline__ void barrier_lds() {
    asm volatile("s_waitcnt lgkmcnt(0)" ::: "memory");
    __builtin_amdgcn_s_barrier();
}

// ---------------------------------------------------------------------------
// Prepack: 6 matrices W[k][n] (256x256 f32, k-major) -> fp16 A-fragment-major:
// idx = ((((c*2+ks)*16 + nhi)*4 + quad)*16 + ln)*8 + j
//   n = nhi*16+ln, k = c*64 + ks*32 + quad*8 + j
// ---------------------------------------------------------------------------
__global__ void prepack(const float* __restrict__ xW1, const float* __restrict__ xW2,
                        const float* __restrict__ xW3, const float* __restrict__ tW1,
                        const float* __restrict__ tW2, const float* __restrict__ tW3,
                        _Float16* __restrict__ dst)
{
    int g = blockIdx.x * 256 + threadIdx.x;   // 6*65536 threads exactly
    int L = g >> 16;
    int r = g & 65535;
    int j    = r & 7;
    int ln   = (r >> 3) & 15;
    int quad = (r >> 7) & 3;
    int nhi  = (r >> 9) & 15;
    int ks   = (r >> 13) & 1;
    int c    = (r >> 14) & 3;
    const float* W;
    switch (L) {
        case 0: W = xW1; break;
        case 1: W = xW2; break;
        case 2: W = xW3; break;
        case 3: W = tW1; break;
        case 4: W = tW2; break;
        default: W = tW3; break;
    }
    int n = nhi * 16 + ln;
    int k = c * 64 + ks * 32 + quad * 8 + j;
    dst[g] = (_Float16)W[k * 256 + n];
}

// ---------------------------------------------------------------------------
// Main fused kernel. Block = 256 threads (4 waves), tile = 64 rows.
// Wave w owns out-channels [w*64, w*64+64) in every 256->256 layer.
// ---------------------------------------------------------------------------

__device__ __forceinline__ void layer0_scalar(
    float xv, const float* __restrict__ W0, const float* __restrict__ b0,
    _Float16* __restrict__ hb, int tid)
{
    int m = tid >> 2;        // 64 rows, 4 threads per row
    int q = tid & 3;
#pragma unroll
    for (int g = 0; g < 8; ++g) {
        int n0 = g * 32 + q * 8;        // 4 q-addresses -> 4 distinct banks
        f16x8 hv;
#pragma unroll
        for (int e = 0; e < 8; ++e) {
            float z = fmaf(xv, W0[n0 + e], b0[n0 + e]);
            hv[e] = (_Float16)__sinf(z);
        }
        *(f16x8*)((char*)hb + hswz(m, n0 * 2)) = hv;
    }
}

// One GEMM phase: acc = Wl x rb (8 K-groups, 16 MFMA each).
// A: afr[2][4] depth-2 register pipeline (refill buf[g&1] for g+2 after
//    last use; g=6/7 load Wnext's g0/g1, staying in flight across barriers).
// B: bfr[2][4] depth-1 LDS pipeline (issue g+1's ds_reads before g's MFMAs).
// MODE 1: slice the OTHER MLP's writeback sin(wacc+bias[LDS]) -> wb_lds,
//         2 of 16 fragments per g. MODE 2: slice layer0_t, 1 group per g.
template<int MODE>   // 0 plain, 1 writeback, 2 layer0-slice
__device__ __forceinline__ void gemm_phase(
    const _Float16* __restrict__ Wl,
    const _Float16* __restrict__ Wnext,    // nullptr at the end
    const _Float16* __restrict__ rb,       // LDS read buffer (activations)
    f32x4 acc[4][4], f16x8 afr[2][4],
    f32x4 wacc[4][4],                      // MODE 1: prev phase's acc
    const float* __restrict__ wbias,       // MODE 1: LDS bias for wacc
    _Float16* __restrict__ wb_lds,         // MODE 1/2: LDS write target
    float xv,                              // MODE 2: scalar input
    const float* __restrict__ W0,          // MODE 2: LDS 1->256 weights
    const float* __restrict__ b0,          // MODE 2: LDS bias
    int tid, int lane, int ln, int quad, int wave)
{
    f32x4 zero = {0.f, 0.f, 0.f, 0.f};
#pragma unroll
    for (int i = 0; i < 4; ++i)
#pragma unroll
        for (int j = 0; j < 4; ++j)
            acc[i][j] = zero;

    const _Float16* abase = Wl + wave * 2048 + lane * 8;

    f16x8 bfr[2][4];
#pragma unroll
    for (int j = 0; j < 4; ++j)          // B prologue: g0 -> buf0
        bfr[0][j] = *(const f16x8*)((const char*)rb +
                                    hswz(16 * j + ln, quad * 16));

#pragma unroll
    for (int g = 0; g < 8; ++g) {
        if (g < 7) {                     // issue g+1's B reads before g's MFMAs
#pragma unroll
            for (int j = 0; j < 4; ++j)
                bfr[(g + 1) & 1][j] = *(const f16x8*)((const char*)rb +
                                 hswz(16 * j + ln, (g + 1) * 64 + quad * 16));
        }

        __builtin_amdgcn_s_setprio(1);
#pragma unroll
        for (int i = 0; i < 4; ++i)
#pragma unroll
            for (int j = 0; j < 4; ++j)
                acc[i][j] = __builtin_amdgcn_mfma_f32_16x16x32_f16(
                    afr[g & 1][i], bfr[g & 1][j], acc[i][j], 0, 0, 0);
        __builtin_amdgcn_s_setprio(0);

        // Refill A buf[g&1] for g+2 (program-order after its last MFMA use).
        if (g < 6) {
#pragma unroll
            for (int i = 0; i < 4; ++i)
                afr[g & 1][i] = *(const f16x8*)(abase + (g + 2) * 8192 + i * 512);
        } else if (Wnext) {              // g=6 -> next g0 (buf0); g=7 -> g1 (buf1)
#pragma unroll
            for (int i = 0; i < 4; ++i)
                afr[g & 1][i] = *(const f16x8*)(Wnext + (g - 6) * 8192 +
                                                wave * 2048 + lane * 8 + i * 512);
        }

        if (MODE == 1) {                 // writeback slice: frag wi, 2 wj's
            const int wi = g >> 1;
            const int nb = wave * 64 + 16 * wi + quad * 4;
            f32x4 bv = *(const f32x4*)&wbias[nb];            // LDS, 4-addr bcast
#pragma unroll
            for (int jo = 0; jo < 2; ++jo) {
                const int wj = (g & 1) * 2 + jo;
                f16x4 hv;
                hv[0] = (_Float16)__sinf(wacc[wi][wj][0] + bv[0]);
                hv[1] = (_Float16)__sinf(wacc[wi][wj][1] + bv[1]);
                hv[2] = (_Float16)__sinf(wacc[wi][wj][2] + bv[2]);
                hv[3] = (_Float16)__sinf(wacc[wi][wj][3] + bv[3]);
                *(f16x4*)((char*)wb_lds + hswz(16 * wj + ln, nb * 2)) = hv;
            }
        } else if (MODE == 2) {          // layer0 slice: one 8-ch group
            const int m = tid >> 2, q = tid & 3;
            const int n0 = g * 32 + q * 8;
            f16x8 hv;
#pragma unroll
            for (int e = 0; e < 8; ++e) {
                float z = fmaf(xv, W0[n0 + e], b0[n0 + e]);
                hv[e] = (_Float16)__sinf(z);
            }
            *(f16x8*)((char*)wb_lds + hswz(m, n0 * 2)) = hv;
        }
    }
}

__global__ __launch_bounds__(256, 2)
void mlp_fused(const float* __restrict__ x,
               const float* __restrict__ xW0, const float* __restrict__ xb0,
               const float* __restrict__ xb1, const float* __restrict__ xb2,
               const float* __restrict__ xb3,
               const float* __restrict__ tW0, const float* __restrict__ tb0,
               const float* __restrict__ tb1, const float* __restrict__ tb2,
               const float* __restrict__ tb3,
               const _Float16* __restrict__ Wp,
               float* __restrict__ out)
{
    __shared__ __align__(16) _Float16 hbuf[2][64 * 256];   // [0]=x acts, [1]=t acts
    __shared__ __align__(16) float    params[10 * 256];    // 10 KB small params

    const int tid = threadIdx.x;
    const int lane = tid & 63;
    const int wave = tid >> 6;       // 0..3
    const int ln = lane & 15;
    const int quad = lane >> 4;
    const int row0 = blockIdx.x * 64;

    // Preload all small params to LDS.
    // segs: 0 xW0, 1 xb0, 2 tW0, 3 tb0, 4 xb1, 5 xb2, 6 xb3, 7 tb1, 8 tb2, 9 tb3
    {
        const float* psrc[10] = {xW0, xb0, tW0, tb0, xb1, xb2, xb3, tb1, tb2, tb3};
#pragma unroll
        for (int s = 0; s < 10; ++s)
            params[s * 256 + tid] = psrc[s][tid];
    }
    const float2 xv2 = ((const float2*)x)[row0 + (tid >> 2)];  // both MLP inputs

    f32x4 xacc[4][4], tacc[4][4];    // 128 AGPR
    f16x8 afr[2][4];                 // A-fragment register double-buffer (32 VGPR)

    // Prologue: xW1 g0 -> buf0, g1 -> buf1; land during layer0_x's sin work.
#pragma unroll
    for (int s = 0; s < 2; ++s)
#pragma unroll
        for (int i = 0; i < 4; ++i)
            afr[s][i] = *(const f16x8*)(Wp + s * 8192 + wave * 2048 +
                                        lane * 8 + i * 512);
    barrier_lds();                    // params visible to all waves

    // ----- layer0_x -----
    layer0_scalar(xv2.x, &params[0], &params[256], hbuf[0], tid);
    barrier_lds();                    // x acts visible

    // ----- 6 alternating GEMM phases -----
    // P1: x1; layer0_t sliced in -> hbuf[1]
    gemm_phase<2>(Wp + 0 * 65536, Wp + 3 * 65536, hbuf[0], xacc, afr,
                  nullptr, nullptr, hbuf[1],
                  xv2.y, &params[2 * 256], &params[3 * 256],
                  tid, lane, ln, quad, wave);
    barrier_lds();
    // P2: t1 || wb_x1 -> hbuf[0]
    gemm_phase<1>(Wp + 3 * 65536, Wp + 1 * 65536, hbuf[1], tacc, afr,
                  xacc, &params[4 * 256], hbuf[0],
                  0.f, nullptr, nullptr, tid, lane, ln, quad, wave);
    barrier_lds();
    // P3: x2 || wb_t1 -> hbuf[1]
    gemm_phase<1>(Wp + 1 * 65536, Wp + 4 * 65536, hbuf[0], xacc, afr,
                  tacc, &params[7 * 256], hbuf[1],
                  0.f, nullptr, nullptr, tid, lane, ln, quad, wave);
    barrier_lds();
    // P4: t2 || wb_x2 -> hbuf[0]
    gemm_phase<1>(Wp + 4 * 65536, Wp + 2 * 65536, hbuf[1], tacc, afr,
                  xacc, &params[5 * 256], hbuf[0],
                  0.f, nullptr, nullptr, tid, lane, ln, quad, wave);
    barrier_lds();
    // P5: x3 || wb_t2 -> hbuf[1]
    gemm_phase<1>(Wp + 2 * 65536, Wp + 5 * 65536, hbuf[0], xacc, afr,
                  tacc, &params[8 * 256], hbuf[1],
                  0.f, nullptr, nullptr, tid, lane, ln, quad, wave);
    barrier_lds();
    // P6: t3
    gemm_phase<0>(Wp + 5 * 65536, nullptr, hbuf[1], tacc, afr,
                  nullptr, nullptr, nullptr,
                  0.f, nullptr, nullptr, tid, lane, ln, quad, wave);

    // ----- combine: even/odd strided dot, fp32 -----
    const float* xb3l = &params[6 * 256];
    const float* tb3l = &params[9 * 256];
    float ev[4] = {0.f, 0.f, 0.f, 0.f};
    float od[4] = {0.f, 0.f, 0.f, 0.f};
#pragma unroll
    for (int i = 0; i < 4; ++i) {
        int nb = wave * 64 + 16 * i + quad * 4;
        f32x4 xb = *(const f32x4*)&xb3l[nb];
        f32x4 tb = *(const f32x4*)&tb3l[nb];
#pragma unroll
        for (int j = 0; j < 4; ++j) {
            float a0 = xacc[i][j][0] + xb[0], c0 = tacc[i][j][0] + tb[0];
            float a1 = xacc[i][j][1] + xb[1], c1 = tacc[i][j][1] + tb[1];
            float a2 = xacc[i][j][2] + xb[2], c2 = tacc[i][j][2] + tb[2];
            float a3 = xacc[i][j][3] + xb[3], c3 = tacc[i][j][3] + tb[3];
            ev[j] += a0 * c0 + a2 * c2;      // channel parity = reg index parity
            od[j] += a1 * c1 + a3 * c3;
        }
    }
#pragma unroll
    for (int j = 0; j < 4; ++j) {            // reduce over the 4 quads
        ev[j] += __shfl_xor(ev[j], 16, 64);
        ev[j] += __shfl_xor(ev[j], 32, 64);
        od[j] += __shfl_xor(od[j], 16, 64);
        od[j] += __shfl_xor(od[j], 32, 64);
    }

    // hbuf[0] dead: its last readers (P5) all passed the P5->P6 barrier.
    float* red = (float*)hbuf[0];
    if (lane < 16) {
#pragma unroll
        for (int j = 0; j < 4; ++j) {
            red[wave * 128 + j * 32 + lane * 2 + 0] = ev[j];
            red[wave * 128 + j * 32 + lane * 2 + 1] = od[j];
        }
    }
    __syncthreads();
    if (tid < 128) {                         // sum the 4 wave partials; coalesced store
        int jj = tid >> 5, m16 = (tid >> 1) & 15, p = tid & 1;
        int base = jj * 32 + m16 * 2 + p;
        float s = red[base] + red[128 + base] + red[256 + base] + red[384 + base];
        out[(row0 + 16 * jj + m16) * 2 + p] = s;
    }
}

// ---------------------------------------------------------------------------
extern "C" void kernel_launch(void* const* d_in, const int* in_sizes, int n_in,
                              void* d_out, int out_size, void* d_ws, size_t ws_size,
                              hipStream_t stream)
{
    const float* x   = (const float*)d_in[0];
    const float* xW0 = (const float*)d_in[1];
    const float* xb0 = (const float*)d_in[2];
    const float* xW1 = (const float*)d_in[3];
    const float* xb1 = (const float*)d_in[4];
    const float* xW2 = (const float*)d_in[5];
    const float* xb2 = (const float*)d_in[6];
    const float* xW3 = (const float*)d_in[7];
    const float* xb3 = (const float*)d_in[8];
    const float* tW0 = (const float*)d_in[9];
    const float* tb0 = (const float*)d_in[10];
    const float* tW1 = (const float*)d_in[11];
    const float* tb1 = (const float*)d_in[12];
    const float* tW2 = (const float*)d_in[13];
    const float* tb2 = (const float*)d_in[14];
    const float* tW3 = (const float*)d_in[15];
    const float* tb3 = (const float*)d_in[16];

    _Float16* Wp = (_Float16*)d_ws;          // 6*65536 fp16 = 768 KB
    const int N = in_sizes[0] / 2;           // 1,000,000 (divisible by 64)

    prepack<<<1536, 256, 0, stream>>>(xW1, xW2, xW3, tW1, tW2, tW3, Wp);
    mlp_fused<<<N / 64, 256, 0, stream>>>(x, xW0, xb0, xb1, xb2, xb3,
                                          tW0, tb0, tb1, tb2, tb3,
                                          Wp, (float*)d_out);
}